// Round 4
// baseline (288.206 us; speedup 1.0000x reference)
//
#include <hip/hip_runtime.h>
#include <math.h>

#define N_NODES 30000
#define F_IN 256
#define E_RAW 300000
#define E_TOT (E_RAW + N_NODES)   /* 330000: edges + self loops */
#define HEADS 8
#define CH 128
#define HC 1024                   /* HEADS*CH */
#define OUTC 64
#define NEG_SLOPE 0.2f
#define CAP 64                    /* edges per LDS chunk in agg2 */
#define LOG2E 1.44269504f
#define MPAD 30080                /* node rows padded for 128-row GEMM tiles */

typedef __attribute__((ext_vector_type(8))) short bf16x8;
typedef __attribute__((ext_vector_type(4))) float f32x4;
typedef __attribute__((ext_vector_type(2))) float f32x2;

/* ---------- helpers ---------- */
__device__ __forceinline__ unsigned short f2bf(float f) {
    unsigned b = __float_as_uint(f);
    b += 0x7FFFu + ((b >> 16) & 1u);   /* round to nearest even */
    return (unsigned short)(b >> 16);
}
__device__ __forceinline__ void edge_sd(const int* __restrict__ ei, int e, int& s, int& d) {
    if (e < E_RAW) { s = ei[e]; d = ei[E_RAW + e]; }
    else           { s = e - E_RAW; d = s; }
}
/* async global->LDS, 16B per lane; LDS dest = wave-uniform base + lane*16 */
__device__ __forceinline__ void async_cp16(const void* g, void* l) {
    __builtin_amdgcn_global_load_lds((const __attribute__((address_space(1))) void*)g,
                                     (__attribute__((address_space(3))) void*)l, 16, 0, 0);
}
/* wave-local LDS handoff (agg2): stop compiler reordering across phases */
__device__ __forceinline__ void wave_sync() {
    __builtin_amdgcn_fence(__ATOMIC_ACQ_REL, "wavefront");
    __builtin_amdgcn_wave_barrier();
}

/* ---------- vsrc: v[j][k] = sum_c W1[k][hj*128+c] * att[hj][c]  (j<8 src, j>=8 dst) ---------- */
__global__ __launch_bounds__(256)
void vsrc_kernel(const float* __restrict__ W1, const float* __restrict__ att_src,
                 const float* __restrict__ att_dst, float* __restrict__ vsd)
{
    const int j = blockIdx.x;          /* 0..15 */
    const int k = threadIdx.x;         /* 0..255 */
    const int hj = j & 7;
    const float* av = (j < 8 ? att_src : att_dst) + hj * CH;
    const float* wr = W1 + (size_t)k * HC + hj * CH;
    float s = 0.f;
#pragma unroll 4
    for (int c = 0; c < CH; c += 4)
        s += wr[c] * av[c] + wr[c + 1] * av[c + 1] + wr[c + 2] * av[c + 2] + wr[c + 3] * av[c + 3];
    vsd[j * 256 + k] = s;
}

/* ---------- fused prep: (cvt x->fp8 + f32 attention dots) | deg | W1t | W2t ----------
   R19: aggregation moved to x-space. Gather payload is x in fp8 (256B/node,
   7.68 MB working set). a_src/a_dst computed EXACTLY in f32 as x . (W1 . att),
   prescaled by log2e. cvt-x job: wave = node (4 nodes/wave to amortize the
   16KB vsd re-read), lane l holds channels 4l..4l+3. */
#define NB_CVTX (N_NODES / 16)                  /* 1875: 16 nodes per block */
#define NB_DEG  ((E_TOT + 255) / 256)           /* 1290 */
#define NB_W1T  ((F_IN * HC + 255) / 256)       /* 1024 */
#define NB_W2T  ((HC * OUTC + 255) / 256)       /* 256 */
#define NB_PREP (NB_CVTX + NB_DEG + NB_W1T + NB_W2T)

__global__ __launch_bounds__(256)
void prep_kernel(const float* __restrict__ x, unsigned* __restrict__ x8,
                 const float* __restrict__ W1, unsigned short* __restrict__ W1t,
                 const float* __restrict__ W2, unsigned short* __restrict__ W2t,
                 const int* __restrict__ ei, int* __restrict__ deg,
                 const float* __restrict__ vsd,
                 float* __restrict__ a_src1, float* __restrict__ a_dst1)
{
    const int b = blockIdx.x, t = threadIdx.x;
    if (b < NB_CVTX) {
        const int w = t >> 6, l = t & 63;
        const int n0 = b * 16 + w * 4;
        float4 vs[16];
        const float4* vs4 = reinterpret_cast<const float4*>(vsd);
#pragma unroll
        for (int j = 0; j < 16; j++) vs[j] = vs4[j * 64 + l];
#pragma unroll 1
        for (int nn = 0; nn < 4; nn++) {
            const int n = n0 + nn;
            const float4 v = reinterpret_cast<const float4*>(x)[(size_t)n * 64 + l];
            unsigned xd = __builtin_amdgcn_cvt_pk_fp8_f32(v.x, v.y, 0, false);
            xd = (unsigned)__builtin_amdgcn_cvt_pk_fp8_f32(v.z, v.w, (int)xd, true);
            x8[(size_t)n * 64 + l] = xd;
            float pp[16];
#pragma unroll
            for (int j = 0; j < 16; j++)
                pp[j] = v.x * vs[j].x + v.y * vs[j].y + v.z * vs[j].z + v.w * vs[j].w;
#pragma unroll
            for (int o = 1; o < 64; o <<= 1)
#pragma unroll
                for (int j = 0; j < 16; j++) pp[j] += __shfl_xor(pp[j], o);
            float sel = pp[0];
#pragma unroll
            for (int j = 1; j < 16; j++) if (l == j) sel = pp[j];
            sel *= LOG2E;
            if (l < 8)       a_src1[n * 8 + l] = sel;
            else if (l < 16) a_dst1[n * 8 + (l - 8)] = sel;
        }
    } else if (b < NB_CVTX + NB_DEG) {
        int e = (b - NB_CVTX) * 256 + t;
        if (e < E_TOT) {
            int s, d; edge_sd(ei, e, s, d);
            atomicAdd(&deg[d], 1);
        }
    } else if (b < NB_CVTX + NB_DEG + NB_W1T) {
        int i = (b - NB_CVTX - NB_DEG) * 256 + t;
        if (i < F_IN * HC) {
            int k = i >> 10, n = i & (HC - 1);
            W1t[n * F_IN + k] = f2bf(W1[i]);
        }
    } else {
        /* W2t[n][k] = W2[k][n] — plain layout (slot permutation removed) */
        int i = (b - NB_CVTX - NB_DEG - NB_W1T) * 256 + t;
        if (i < HC * OUTC) {
            int k = i >> 6, n = i & (OUTC - 1);
            W2t[n * HC + k] = f2bf(W2[k * OUTC + n]);
        }
    }
}

/* ---------- CSR build ---------- */
__global__ __launch_bounds__(256)
void alloc_kernel(const int* __restrict__ deg, int* __restrict__ rowstart,
                  int* __restrict__ cursor, int* __restrict__ counter)
{
    int d = blockIdx.x * 256 + threadIdx.x;
    int lane = threadIdx.x & 63;
    int v = (d < N_NODES) ? deg[d] : 0;
    int x = v;
#pragma unroll
    for (int o = 1; o < 64; o <<= 1) {
        int y = __shfl_up(x, o);
        if (lane >= o) x += y;
    }
    int excl = x - v;
    int total = __shfl(x, 63);
    int base = 0;
    if (lane == 63) base = atomicAdd(counter, total);
    base = __shfl(base, 63);
    if (d < N_NODES) {
        rowstart[d] = base + excl;
        cursor[d]   = base + excl;
    }
}

__global__ void scatter_kernel(const int* __restrict__ ei, int* __restrict__ cursor,
                               int* __restrict__ csr_src)
{
    int e = blockIdx.x * 256 + threadIdx.x;
    if (e >= E_TOT) return;
    int s, d; edge_sd(ei, e, s, d);
    int pos = atomicAdd(&cursor[d], 1);
    csr_src[pos] = s;
}

/* ---------- aggx: softmax-weighted aggregation of x (fp8), per head ----------
   Replaces the old h1p gather (1KB/edge, 30.7MB ws) with a 256B/edge gather
   over a 7.68MB working set (L2-resident per XCD model: FETCH should collapse).
   wave = node d; lane l: channels 4l..4l+3, weight-lane for head l&7.
   All lanes see every edge -> per-lane denominator is already complete.
   Output: aggx[d][h][k] = (1/denom_h) sum_s w_sh * x_fp8[s][k]   (bf16). */
struct GX4 { int s[4]; };
struct VX4 { float a[4]; unsigned x[4]; };

__device__ __forceinline__ GX4 gx4_load(const int* __restrict__ csr, int start, int c, int dm) {
    GX4 g;
#pragma unroll
    for (int j = 0; j < 4; j++) g.s[j] = csr[start + min(c + j, dm)];
    return g;
}
__device__ __forceinline__ VX4 vx4_load(const float* __restrict__ a_src1,
                                        const unsigned* __restrict__ x8,
                                        GX4 g, int hh, int tl) {
    VX4 r;
#pragma unroll
    for (int j = 0; j < 4; j++) {
        r.a[j] = a_src1[g.s[j] * 8 + hh];
        r.x[j] = x8[(size_t)g.s[j] * 64 + tl];
    }
    return r;
}

#define XEDGE(lg_, xd_) do { \
    float v_ = fmaxf((lg_), NEG_SLOPE * (lg_)); \
    float w_ = __builtin_amdgcn_exp2f(v_); \
    dn += w_; \
    float wh_[8]; \
    _Pragma("unroll") \
    for (int q_ = 0; q_ < 8; q_++) wh_[q_] = __shfl(w_, lb | q_); \
    f32x2 lo_ = __builtin_amdgcn_cvt_pk_f32_fp8((int)(xd_), false); \
    f32x2 hi_ = __builtin_amdgcn_cvt_pk_f32_fp8((int)(xd_), true); \
    _Pragma("unroll") \
    for (int q_ = 0; q_ < 8; q_++) { \
        acc[q_][0] += wh_[q_] * lo_.x; \
        acc[q_][1] += wh_[q_] * lo_.y; \
        acc[q_][2] += wh_[q_] * hi_.x; \
        acc[q_][3] += wh_[q_] * hi_.y; \
    } \
} while (0)

__global__ __launch_bounds__(256)
void aggx_kernel(const int* __restrict__ rowstart, const int* __restrict__ degv,
                 const int* __restrict__ csr_src,
                 const unsigned* __restrict__ x8,      /* [N][64] fp8 dwords */
                 const float* __restrict__ a_src1, const float* __restrict__ a_dst1,
                 unsigned short* __restrict__ aggx)    /* [MPAD][8][256] bf16 */
{
    const int t   = threadIdx.x;
    const int sub = t >> 6;            /* node within block (= wave) */
    const int tl  = t & 63;
    const int hh  = tl & 7;            /* weight head for this lane */
    const int lb  = tl & 56;
    const int d   = blockIdx.x * 4 + sub;

    const int start = __builtin_amdgcn_readfirstlane(rowstart[d]);
    const int deg   = __builtin_amdgcn_readfirstlane(degv[d]);
    const int dm    = deg - 1;
    const float adst = a_dst1[d * 8 + hh];   /* prescaled by log2e */

    float dn = 0.f;
    float acc[8][4];
#pragma unroll
    for (int h = 0; h < 8; h++)
#pragma unroll
        for (int k = 0; k < 4; k++) acc[h][k] = 0.f;

    GX4 sC = gx4_load(csr_src, start, 0, dm);
    VX4 vC = vx4_load(a_src1, x8, sC, hh, tl);
    GX4 sN = gx4_load(csr_src, start, 4, dm);

#pragma unroll 1
    for (int c = 0; c < deg; c += 4) {
        const bool more = (c + 4 < deg);    /* wave-uniform */
        VX4 vN;
        if (more) { vN = vx4_load(a_src1, x8, sN, hh, tl); sN = gx4_load(csr_src, start, c + 8, dm); }
        if (c + 4 <= deg) {
            XEDGE(vC.a[0] + adst, vC.x[0]);
            XEDGE(vC.a[1] + adst, vC.x[1]);
            XEDGE(vC.a[2] + adst, vC.x[2]);
            XEDGE(vC.a[3] + adst, vC.x[3]);
        } else {
            float l0 = (c + 0 < deg) ? vC.a[0] + adst : -1e30f; XEDGE(l0, vC.x[0]);
            float l1 = (c + 1 < deg) ? vC.a[1] + adst : -1e30f; XEDGE(l1, vC.x[1]);
            float l2 = (c + 2 < deg) ? vC.a[2] + adst : -1e30f; XEDGE(l2, vC.x[2]);
            float l3 = (c + 3 < deg) ? vC.a[3] + adst : -1e30f; XEDGE(l3, vC.x[3]);
        }
        if (more) vC = vN;
    }

    /* dn is already the full denominator for head hh (every lane saw every edge) */
    const float dinv = 1.f / (dn + 1e-16f);
    unsigned short* ag = aggx + (size_t)d * 2048 + 4 * tl;
#pragma unroll
    for (int h = 0; h < 8; h++) {
        float di = __shfl(dinv, lb | h);
        ushort4 o;
        o.x = f2bf(acc[h][0] * di);
        o.y = f2bf(acc[h][1] * di);
        o.z = f2bf(acc[h][2] * di);
        o.w = f2bf(acc[h][3] * di);
        *reinterpret_cast<ushort4*>(ag + h * 256) = o;
    }
}

/* ---------- layer-1 block-diagonal GEMM: out1 = ELU(aggx @ W1 + b1) ----------
   8 independent [N x 256]@[256 x 128] GEMMs (head h = blockIdx.x). Same tile
   structure as the old gemm1 (128x128 tile, BK=64, XOR-swizzled LDS); A is the
   head's K-slice of aggx (row stride 2048). Epilogue: bias + ELU, plain bf16. */
__global__ __launch_bounds__(256)
void gemm1b(const unsigned short* __restrict__ A,   /* aggx [MPAD][2048] bf16 */
            const unsigned short* __restrict__ Bt,  /* W1t  [1024][256] bf16  */
            const float* __restrict__ b1,
            unsigned short* __restrict__ out1, int M)
{
    __shared__ unsigned short Al[128 * 64];
    __shared__ unsigned short Bl[128 * 64];
    const int tid  = threadIdx.x;
    const int wave = tid >> 6, lane = tid & 63;
    const int quad = lane >> 4, l16 = lane & 15;
    const int wr = (wave >> 1) * 64, wc = (wave & 1) * 64;
    const int row0 = blockIdx.y * 128;
    const int col0 = blockIdx.x * 128;      /* output cols of head */
    const int ak0  = blockIdx.x * 256;      /* A K-slice offset of head */

    f32x4 acc[4][4];
#pragma unroll
    for (int i = 0; i < 4; i++)
#pragma unroll
        for (int j = 0; j < 4; j++) acc[i][j] = (f32x4){0.f, 0.f, 0.f, 0.f};

    for (int k0 = 0; k0 < F_IN; k0 += 64) {
#pragma unroll
        for (int p = 0; p < 4; p++) {           /* A: 128 rows x 64 bf16, swizzled */
            int idx = tid + 256 * p;
            int r = idx >> 3, q = idx & 7;
            async_cp16(A + (size_t)(row0 + r) * 2048 + ak0 + k0 + ((q ^ (r & 7)) * 8),
                       Al + (size_t)(wave * 64 + 256 * p) * 8);
        }
#pragma unroll
        for (int p = 0; p < 4; p++) {           /* B^T: 128 rows x 64 bf16, swizzled */
            int idx = tid + 256 * p;
            int r = idx >> 3, q = idx & 7;
            async_cp16(Bt + (size_t)(col0 + r) * F_IN + k0 + ((q ^ (r & 7)) * 8),
                       Bl + (size_t)(wave * 64 + 256 * p) * 8);
        }
        __syncthreads();
#pragma unroll
        for (int kh = 0; kh < 2; kh++) {
            const int cx = (kh * 4 + quad) ^ (l16 & 7);
            bf16x8 af[4], bg[4];
#pragma unroll
            for (int i = 0; i < 4; i++)
                af[i] = *reinterpret_cast<const bf16x8*>(Al + ((wr + i * 16 + l16) * 8 + cx) * 8);
#pragma unroll
            for (int j = 0; j < 4; j++)
                bg[j] = *reinterpret_cast<const bf16x8*>(Bl + ((wc + j * 16 + l16) * 8 + cx) * 8);
#pragma unroll
            for (int i = 0; i < 4; i++)
#pragma unroll
                for (int j = 0; j < 4; j++)
                    acc[i][j] = __builtin_amdgcn_mfma_f32_16x16x32_bf16(af[i], bg[j], acc[i][j], 0, 0, 0);
        }
        __syncthreads();
    }
    float bb[4];
#pragma unroll
    for (int j = 0; j < 4; j++) bb[j] = b1[col0 + wc + j * 16 + l16];
#pragma unroll
    for (int i = 0; i < 4; i++) {
#pragma unroll
        for (int r = 0; r < 4; r++) {
            int row = row0 + wr + i * 16 + quad * 4 + r;
            if (row >= M) continue;
#pragma unroll
            for (int j = 0; j < 4; j++) {
                float v = acc[i][j][r] + bb[j];
                v = v > 0.f ? v : __expf(v) - 1.f;
                out1[(size_t)row * HC + col0 + wc + j * 16 + l16] = f2bf(v);
            }
        }
    }
}

/* ---------- layer-2 MFMA GEMM + fused att2 dots ----------
   64-row tiles, BK=64 swizzled; wave w owns rows w*16..w*16+15. */
__global__ __launch_bounds__(256)
void gemm2_mfma(const unsigned short* __restrict__ A,
                const unsigned short* __restrict__ Bt,
                unsigned short* __restrict__ C,
                const float* __restrict__ att_src2, const float* __restrict__ att_dst2,
                float* __restrict__ a_src2, float* __restrict__ a_dst2, int M)
{
    __shared__ unsigned short Al[64 * 64];
    __shared__ unsigned short Bl[64 * 64];
    const int tid  = threadIdx.x;
    const int wave = tid >> 6, lane = tid & 63;
    const int quad = lane >> 4, l16 = lane & 15;
    const int wr = wave * 16;
    const int row0 = blockIdx.x * 64;

    f32x4 acc[4];
#pragma unroll
    for (int j = 0; j < 4; j++) acc[j] = (f32x4){0.f, 0.f, 0.f, 0.f};

    for (int k0 = 0; k0 < HC; k0 += 64) {
#pragma unroll
        for (int p = 0; p < 2; p++) {           /* A: 64 rows x 64 bf16, swizzled */
            int idx = tid + 256 * p;
            int r = idx >> 3, q = idx & 7;
            async_cp16(A + (size_t)(row0 + r) * HC + k0 + ((q ^ (r & 7)) * 8),
                       Al + (size_t)(wave * 64 + 256 * p) * 8);
        }
#pragma unroll
        for (int p = 0; p < 2; p++) {           /* B^T: 64 rows x 64 bf16, swizzled */
            int idx = tid + 256 * p;
            int r = idx >> 3, q = idx & 7;
            async_cp16(Bt + (size_t)r * HC + k0 + ((q ^ (r & 7)) * 8),
                       Bl + (size_t)(wave * 64 + 256 * p) * 8);
        }
        __syncthreads();
#pragma unroll
        for (int kh = 0; kh < 2; kh++) {
            const int cx = (kh * 4 + quad) ^ (l16 & 7);
            bf16x8 af, bg[4];
            af = *reinterpret_cast<const bf16x8*>(Al + ((wr + l16) * 8 + cx) * 8);
#pragma unroll
            for (int j = 0; j < 4; j++)
                bg[j] = *reinterpret_cast<const bf16x8*>(Bl + ((j * 16 + l16) * 8 + cx) * 8);
#pragma unroll
            for (int j = 0; j < 4; j++)
                acc[j] = __builtin_amdgcn_mfma_f32_16x16x32_bf16(af, bg[j], acc[j], 0, 0, 0);
        }
        __syncthreads();
    }
    float av[4], dv[4];
#pragma unroll
    for (int j = 0; j < 4; j++) {
        av[j] = att_src2[j * 16 + l16];
        dv[j] = att_dst2[j * 16 + l16];
    }
#pragma unroll
    for (int r = 0; r < 4; r++) {
        int row = row0 + wr + quad * 4 + r;
        float ps = 0.f, pd = 0.f;
#pragma unroll
        for (int j = 0; j < 4; j++) {
            float cc = acc[j][r];
            int col = j * 16 + l16;
            if (row < M) C[(size_t)row * OUTC + col] = f2bf(cc);
            ps += cc * av[j];
            pd += cc * dv[j];
        }
#pragma unroll
        for (int o = 1; o < 16; o <<= 1) {
            ps += __shfl_xor(ps, o);
            pd += __shfl_xor(pd, o);
        }
        if (l16 == 0 && row < M) {
            a_src2[row] = ps;
            a_dst2[row] = pd;
        }
    }
}

/* ---------- layer-2 fused softmax+agg + bias + log_softmax ---------- */
__global__ __launch_bounds__(256)
void agg2_lsm(const int* __restrict__ rowstart, const int* __restrict__ degv,
              const int* __restrict__ csr_src,
              const unsigned short* __restrict__ h2,
              const float* __restrict__ a_src2, const float* __restrict__ a_dst2,
              const float* __restrict__ b2, float* __restrict__ out)
{
    const int t = threadIdx.x;
    const int sub  = t >> 6;
    const int lane = t & 63;
    const int eo   = lane >> 4;        /* edge offset 0..3 */
    const int cq   = lane & 15;        /* channel quad: channels 4cq..4cq+3 */
    const int d = blockIdx.x * 4 + sub;

    __shared__ float exs[4][CAP];
    __shared__ int   ss[4][CAP];

    const int start = rowstart[d];
    const int deg   = degv[d];

    const float adst = a_dst2[d];
    const uint2* __restrict__ h2v = reinterpret_cast<const uint2*>(h2);  /* row = 16 uint2 */
    float denom_part = 0.f;
    float ax = 0.f, ay = 0.f, az = 0.f, aw = 0.f;

    for (int c0 = 0; c0 < deg; c0 += CAP) {
        const int cend = min(deg - c0, CAP);
        for (int c = lane; c < cend; c += 64) {
            int s = csr_src[start + c0 + c];
            ss[sub][c] = s;
            float a = a_src2[s] + adst;
            float v = a > 0.f ? a : NEG_SLOPE * a;
            float ex = __expf(v);
            exs[sub][c] = ex;
            denom_part += ex;
        }
        wave_sync();
        {
            int   cc = eo;
            float w0 = (cc < cend) ? exs[sub][cc] : 0.f;
            int   s0 = (cc < cend) ? ss[sub][cc] : ss[sub][0];
            uint2 u0 = h2v[(size_t)s0 * 16 + cq];
            for (int c = 0; c + 4 < cend; c += 4) {
                int cc1 = c + 4 + eo;
                float w1 = (cc1 < cend) ? exs[sub][cc1] : 0.f;
                int   s1 = (cc1 < cend) ? ss[sub][cc1] : ss[sub][0];
                uint2 u1 = h2v[(size_t)s1 * 16 + cq];
                ax += w0 * __uint_as_float(u0.x << 16);
                ay += w0 * __uint_as_float(u0.x & 0xFFFF0000u);
                az += w0 * __uint_as_float(u0.y << 16);
                aw += w0 * __uint_as_float(u0.y & 0xFFFF0000u);
                w0 = w1; s0 = s1; u0 = u1;
            }
            ax += w0 * __uint_as_float(u0.x << 16);
            ay += w0 * __uint_as_float(u0.x & 0xFFFF0000u);
            az += w0 * __uint_as_float(u0.y << 16);
            aw += w0 * __uint_as_float(u0.y & 0xFFFF0000u);
        }
        wave_sync();
    }
    ax += __shfl_xor(ax, 16); ax += __shfl_xor(ax, 32);
    ay += __shfl_xor(ay, 16); ay += __shfl_xor(ay, 32);
    az += __shfl_xor(az, 16); az += __shfl_xor(az, 32);
    aw += __shfl_xor(aw, 16); aw += __shfl_xor(aw, 32);
#pragma unroll
    for (int o = 32; o > 0; o >>= 1) denom_part += __shfl_xor(denom_part, o);
    const float dinv = 1.f / (denom_part + 1e-16f);

    float4 bb = reinterpret_cast<const float4*>(b2)[cq];
    float v0 = ax * dinv + bb.x;
    float v1 = ay * dinv + bb.y;
    float v2 = az * dinv + bb.z;
    float v3 = aw * dinv + bb.w;
    float m = fmaxf(fmaxf(v0, v1), fmaxf(v2, v3));
#pragma unroll
    for (int o = 1; o < 16; o <<= 1) m = fmaxf(m, __shfl_xor(m, o));
    float ex = __expf(v0 - m) + __expf(v1 - m) + __expf(v2 - m) + __expf(v3 - m);
    float ssum = ex;
#pragma unroll
    for (int o = 1; o < 16; o <<= 1) ssum += __shfl_xor(ssum, o);
    if (eo == 0) {
        float lg = __logf(ssum);
        reinterpret_cast<float4*>(out + (size_t)d * OUTC)[cq] =
            make_float4(v0 - m - lg, v1 - m - lg, v2 - m - lg, v3 - m - lg);
    }
}

extern "C" void kernel_launch(void* const* d_in, const int* in_sizes, int n_in,
                              void* d_out, int out_size, void* d_ws, size_t ws_size,
                              hipStream_t stream)
{
    const float* x   = (const float*)d_in[0];
    const int*   ei  = (const int*)d_in[1];
    const float* W1  = (const float*)d_in[2];
    const float* as1 = (const float*)d_in[3];
    const float* ad1 = (const float*)d_in[4];
    const float* b1  = (const float*)d_in[5];
    const float* W2  = (const float*)d_in[6];
    const float* as2 = (const float*)d_in[7];
    const float* ad2 = (const float*)d_in[8];
    const float* b2  = (const float*)d_in[9];

    char* p = (char*)d_ws;
    auto alloc = [&](size_t bytes) { char* r = p; p += (bytes + 255) & ~(size_t)255; return r; };

    /* region P: aggx bf16 [MPAD][2048] (123.2 MB); h2/a2 alias after gemm1b */
    char* regionP = (char*)alloc((size_t)MPAD * 2048 * 2);
    unsigned short* aggx = (unsigned short*)regionP;

    /* region Q: x8 (7.68 MB, dead after aggx) then out1 (61.5 MB incl. tile pad) */
    char* regionQ = (char*)alloc((size_t)(N_NODES + 16) * HC * 2);
    unsigned short* out1 = (unsigned short*)regionQ;
    unsigned* x8 = (unsigned*)regionQ;

    unsigned short* W1t = (unsigned short*)alloc((size_t)F_IN * HC * 2);
    unsigned short* W2t = (unsigned short*)alloc((size_t)OUTC * HC * 2);
    float* vsd = (float*)alloc(16 * 256 * 4);

    float* a_src1   = (float*)alloc((size_t)N_NODES * HEADS * 4);
    float* a_dst1   = (float*)alloc((size_t)N_NODES * HEADS * 4);
    int*   deg      = (int*)alloc((size_t)(N_NODES + 1) * 4);  /* +1: alloc counter */
    int*   counter  = deg + N_NODES;
    int*   rowstart = (int*)alloc((size_t)N_NODES * 4);
    int*   cursor   = (int*)alloc((size_t)N_NODES * 4);
    int*   csr_src  = (int*)alloc((size_t)E_TOT * 4);

    /* layer-2 buffers alias regionP (aggx dead after gemm1b) */
    char* q = regionP;
    auto alias = [&](size_t bytes) { char* r = q; q += (bytes + 255) & ~(size_t)255; return r; };
    unsigned short* h2 = (unsigned short*)alias((size_t)N_NODES * OUTC * 2);
    float* a_src2  = (float*)alias((size_t)N_NODES * 4);
    float* a_dst2  = (float*)alias((size_t)N_NODES * 4);

    hipMemsetAsync(deg, 0, (size_t)(N_NODES + 1) * 4, stream);

    /* v = W1 . att (f32, tiny) -> prep needs it for the attention dots */
    vsrc_kernel<<<16, 256, 0, stream>>>(W1, as1, ad1, vsd);

    /* fused prep: (x->fp8 + f32 att dots) | deg | W1t | W2t */
    prep_kernel<<<NB_PREP, 256, 0, stream>>>(x, x8, W1, W1t, W2, W2t, ei, deg,
                                             vsd, a_src1, a_dst1);

    /* CSR build */
    alloc_kernel<<<(N_NODES + 255) / 256, 256, 0, stream>>>(deg, rowstart, cursor, counter);
    scatter_kernel<<<(E_TOT + 255) / 256, 256, 0, stream>>>(ei, cursor, csr_src);

    /* layer 1: aggregate x in fp8 (softmax in x-space), then block-diagonal GEMM */
    aggx_kernel<<<N_NODES / 4, 256, 0, stream>>>(rowstart, deg, csr_src, x8,
                                                 a_src1, a_dst1, aggx);
    gemm1b<<<dim3(HEADS, (N_NODES + 127) / 128), 256, 0, stream>>>(aggx, W1t, b1, out1, N_NODES);

    /* layer 2 (aggx dead; aliased buffers safe, stream-ordered) */
    gemm2_mfma<<<(N_NODES + 63) / 64, 256, 0, stream>>>(
        out1, W2t, h2, as2, ad2, a_src2, a_dst2, N_NODES);
    agg2_lsm<<<N_NODES / 4, 256, 0, stream>>>(rowstart, deg, csr_src, h2, a_src2, a_dst2, b2, (float*)d_out);
}

// Round 5
// 272.036 us; speedup vs baseline: 1.0594x; 1.0594x over previous
//
#include <hip/hip_runtime.h>
#include <math.h>

#define N_NODES 30000
#define F_IN 256
#define E_RAW 300000
#define E_TOT (E_RAW + N_NODES)   /* 330000: edges + self loops */
#define HEADS 8
#define CH 128
#define HC 1024                   /* HEADS*CH */
#define OUTC 64
#define NEG_SLOPE 0.2f
#define CAP 64                    /* edges per LDS chunk in agg kernels */
#define LOG2E 1.44269504f

typedef __attribute__((ext_vector_type(8))) short bf16x8;
typedef __attribute__((ext_vector_type(4))) float f32x4;
typedef __attribute__((ext_vector_type(2))) float f32x2;

/* ---------- helpers ---------- */
__device__ __forceinline__ unsigned short f2bf(float f) {
    unsigned b = __float_as_uint(f);
    b += 0x7FFFu + ((b >> 16) & 1u);   /* round to nearest even */
    return (unsigned short)(b >> 16);
}
__device__ __forceinline__ void edge_sd(const int* __restrict__ ei, int e, int& s, int& d) {
    if (e < E_RAW) { s = ei[e]; d = ei[E_RAW + e]; }
    else           { s = e - E_RAW; d = s; }
}
/* async global->LDS, 16B per lane; LDS dest = wave-uniform base + lane*16 */
__device__ __forceinline__ void async_cp16(const void* g, void* l) {
    __builtin_amdgcn_global_load_lds((const __attribute__((address_space(1))) void*)g,
                                     (__attribute__((address_space(3))) void*)l, 16, 0, 0);
}
/* fp8 slot permutation: slot s -> original channel */
__device__ __forceinline__ int slotP(int s) {
    return ((s >> 6) << 6) + ((s >> 2) & 15) + ((s & 3) << 4);
}
/* wave-local LDS handoff: stop compiler reordering across phases */
__device__ __forceinline__ void wave_sync() {
    __builtin_amdgcn_fence(__ATOMIC_ACQ_REL, "wavefront");
    __builtin_amdgcn_wave_barrier();
}
/* packed 2xf32 FMA */
__device__ __forceinline__ f32x2 pk_fma(f32x2 a, f32x2 b, f32x2 c) {
    f32x2 d;
    asm("v_pk_fma_f32 %0, %1, %2, %3" : "=v"(d) : "v"(a), "v"(b), "v"(c));
    return d;
}
/* leaky + exp2 (inputs prescaled by log2e) */
__device__ __forceinline__ float wexp(float t) {
    return __builtin_amdgcn_exp2f(fmaxf(t, NEG_SLOPE * t));
}

/* ---------- vsrc: v[j][k] = sum_c W1[k][hj*128+c] * att[hj][c]  (j<8 src, j>=8 dst) ---------- */
__global__ __launch_bounds__(256)
void vsrc_kernel(const float* __restrict__ W1, const float* __restrict__ att_src,
                 const float* __restrict__ att_dst, float* __restrict__ vsd)
{
    const int j = blockIdx.x;          /* 0..15 */
    const int k = threadIdx.x;         /* 0..255 */
    const int hj = j & 7;
    const float* av = (j < 8 ? att_src : att_dst) + hj * CH;
    const float* wr = W1 + (size_t)k * HC + hj * CH;
    float s = 0.f;
#pragma unroll 4
    for (int c = 0; c < CH; c += 4)
        s += wr[c] * av[c] + wr[c + 1] * av[c + 1] + wr[c + 2] * av[c + 2] + wr[c + 3] * av[c + 3];
    vsd[j * 256 + k] = s;
}

/* ---------- fused prep: (cvt x->bf16 + f32 attention dots) | deg | W1t | W2t ----------
   R20: a_src/a_dst computed EXACTLY in f32 as x . (W1 . att), prescaled by
   log2e, BEFORE the CSR build — so scatter can precompute per-edge weights. */
#define NB_CVTX (N_NODES / 16)                  /* 1875: 16 nodes per block */
#define NB_DEG  ((E_TOT + 255) / 256)           /* 1290 */
#define NB_W1T  ((F_IN * HC + 255) / 256)       /* 1024 */
#define NB_W2T  ((HC * OUTC + 255) / 256)       /* 256 */
#define NB_PREP (NB_CVTX + NB_DEG + NB_W1T + NB_W2T)

__global__ __launch_bounds__(256)
void prep_kernel(const float* __restrict__ x, unsigned short* __restrict__ xb,
                 const float* __restrict__ W1, unsigned short* __restrict__ W1t,
                 const float* __restrict__ W2, unsigned short* __restrict__ W2t,
                 const int* __restrict__ ei, int* __restrict__ deg,
                 const float* __restrict__ vsd,
                 float* __restrict__ a_src1, float* __restrict__ a_dst1)
{
    const int b = blockIdx.x, t = threadIdx.x;
    if (b < NB_CVTX) {
        const int w = t >> 6, l = t & 63;
        const int n0 = b * 16 + w * 4;
        float4 vs[16];
        const float4* vs4 = reinterpret_cast<const float4*>(vsd);
#pragma unroll
        for (int j = 0; j < 16; j++) vs[j] = vs4[j * 64 + l];
#pragma unroll 1
        for (int nn = 0; nn < 4; nn++) {
            const int n = n0 + nn;
            const float4 v = reinterpret_cast<const float4*>(x)[(size_t)n * 64 + l];
            ushort4 o;
            o.x = f2bf(v.x); o.y = f2bf(v.y); o.z = f2bf(v.z); o.w = f2bf(v.w);
            reinterpret_cast<ushort4*>(xb)[(size_t)n * 64 + l] = o;
            float pp[16];
#pragma unroll
            for (int j = 0; j < 16; j++)
                pp[j] = v.x * vs[j].x + v.y * vs[j].y + v.z * vs[j].z + v.w * vs[j].w;
#pragma unroll
            for (int o2 = 1; o2 < 64; o2 <<= 1)
#pragma unroll
                for (int j = 0; j < 16; j++) pp[j] += __shfl_xor(pp[j], o2);
            float sel = pp[0];
#pragma unroll
            for (int j = 1; j < 16; j++) if (l == j) sel = pp[j];
            sel *= LOG2E;
            if (l < 8)       a_src1[n * 8 + l] = sel;
            else if (l < 16) a_dst1[n * 8 + (l - 8)] = sel;
        }
    } else if (b < NB_CVTX + NB_DEG) {
        int e = (b - NB_CVTX) * 256 + t;
        if (e < E_TOT) {
            int s, d; edge_sd(ei, e, s, d);
            atomicAdd(&deg[d], 1);
        }
    } else if (b < NB_CVTX + NB_DEG + NB_W1T) {
        int i = (b - NB_CVTX - NB_DEG) * 256 + t;
        if (i < F_IN * HC) {
            int k = i >> 10, n = i & (HC - 1);
            W1t[n * F_IN + k] = f2bf(W1[i]);
        }
    } else {
        /* W2t[n][s] = W2[P(s)][n] — k-axis carries the out1 slot permutation */
        int i = (b - NB_CVTX - NB_DEG - NB_W1T) * 256 + t;
        if (i < HC * OUTC) {
            int s = i >> 6, n = i & (OUTC - 1);
            W2t[n * HC + s] = f2bf(W2[slotP(s) * OUTC + n]);
        }
    }
}

/* ---------- CSR build ---------- */
__global__ __launch_bounds__(256)
void alloc_kernel(const int* __restrict__ deg, int* __restrict__ rowstart,
                  int* __restrict__ cursor, int* __restrict__ counter)
{
    int d = blockIdx.x * 256 + threadIdx.x;
    int lane = threadIdx.x & 63;
    int v = (d < N_NODES) ? deg[d] : 0;
    int x = v;
#pragma unroll
    for (int o = 1; o < 64; o <<= 1) {
        int y = __shfl_up(x, o);
        if (lane >= o) x += y;
    }
    int excl = x - v;
    int total = __shfl(x, 63);
    int base = 0;
    if (lane == 63) base = atomicAdd(counter, total);
    base = __shfl(base, 63);
    if (d < N_NODES) {
        rowstart[d] = base + excl;
        cursor[d]   = base + excl;
    }
}

/* ---------- scatter + per-edge weight precompute ----------
   R20: a_src1/a_dst1 are ready (prep f32 dots), so the random a-gathers and
   the leaky/exp chain run HERE, edge-parallel (latency hidden by 330K-thread
   TLP), instead of inside agg1's per-node serial loop. wcsr[pos][8] f32. */
__global__ void scatter_kernel(const int* __restrict__ ei, int* __restrict__ cursor,
                               int* __restrict__ csr_src,
                               const float* __restrict__ a_src1,
                               const float* __restrict__ a_dst1,
                               float* __restrict__ wcsr)
{
    int e = blockIdx.x * 256 + threadIdx.x;
    if (e >= E_TOT) return;
    int s, d; edge_sd(ei, e, s, d);
    int pos = atomicAdd(&cursor[d], 1);
    csr_src[pos] = s;
    const float4* A4 = reinterpret_cast<const float4*>(a_src1);
    const float4* D4 = reinterpret_cast<const float4*>(a_dst1);
    float4 sa = A4[s * 2 + 0], sb = A4[s * 2 + 1];
    float4 da = D4[d * 2 + 0], db = D4[d * 2 + 1];
    float4 w0, w1;
    w0.x = wexp(sa.x + da.x); w0.y = wexp(sa.y + da.y);
    w0.z = wexp(sa.z + da.z); w0.w = wexp(sa.w + da.w);
    w1.x = wexp(sb.x + db.x); w1.y = wexp(sb.y + db.y);
    w1.z = wexp(sb.z + db.z); w1.w = wexp(sb.w + db.w);
    reinterpret_cast<float4*>(wcsr)[pos * 2 + 0] = w0;
    reinterpret_cast<float4*>(wcsr)[pos * 2 + 1] = w1;
}

/* ---------- layer-1 MFMA GEMM, fp8 slot-layout C (R13 form, dots removed) ---------- */
__global__ __launch_bounds__(256)
void gemm1_mfma(const unsigned short* __restrict__ A,
                const unsigned short* __restrict__ Bt,
                unsigned* __restrict__ Cp,      /* [M][256] dwords, fp8 slots */
                int M)
{
    __shared__ unsigned short Al[128 * 64];
    __shared__ unsigned short Bl[128 * 64];
    const int tid  = threadIdx.x;
    const int wave = tid >> 6, lane = tid & 63;
    const int quad = lane >> 4, l16 = lane & 15;
    const int wr = (wave >> 1) * 64, wc = (wave & 1) * 64;
    const int row0 = blockIdx.y * 128;
    const int col0 = blockIdx.x * 128;

    f32x4 acc[4][4];
#pragma unroll
    for (int i = 0; i < 4; i++)
#pragma unroll
        for (int j = 0; j < 4; j++) acc[i][j] = (f32x4){0.f, 0.f, 0.f, 0.f};

    for (int k0 = 0; k0 < F_IN; k0 += 64) {
#pragma unroll
        for (int p = 0; p < 4; p++) {           /* A: 128 rows x 64 bf16, swizzled */
            int idx = tid + 256 * p;
            int r = idx >> 3, q = idx & 7;
            async_cp16(A + (size_t)(row0 + r) * F_IN + k0 + ((q ^ (r & 7)) * 8),
                       Al + (size_t)(wave * 64 + 256 * p) * 8);
        }
#pragma unroll
        for (int p = 0; p < 4; p++) {           /* B^T: 128 rows x 64 bf16, swizzled */
            int idx = tid + 256 * p;
            int r = idx >> 3, q = idx & 7;
            async_cp16(Bt + (size_t)(col0 + r) * F_IN + k0 + ((q ^ (r & 7)) * 8),
                       Bl + (size_t)(wave * 64 + 256 * p) * 8);
        }
        __syncthreads();
#pragma unroll
        for (int kh = 0; kh < 2; kh++) {
            const int cx = (kh * 4 + quad) ^ (l16 & 7);
            bf16x8 af[4], bg[4];
#pragma unroll
            for (int i = 0; i < 4; i++)
                af[i] = *reinterpret_cast<const bf16x8*>(Al + ((wr + i * 16 + l16) * 8 + cx) * 8);
#pragma unroll
            for (int j = 0; j < 4; j++)
                bg[j] = *reinterpret_cast<const bf16x8*>(Bl + ((wc + j * 16 + l16) * 8 + cx) * 8);
#pragma unroll
            for (int i = 0; i < 4; i++)
#pragma unroll
                for (int j = 0; j < 4; j++)
                    acc[i][j] = __builtin_amdgcn_mfma_f32_16x16x32_bf16(af[i], bg[j], acc[i][j], 0, 0, 0);
        }
        __syncthreads();
    }
    const int D = ((col0 + wc) >> 6) * 16 + l16;
#pragma unroll
    for (int i = 0; i < 4; i++) {
#pragma unroll
        for (int r = 0; r < 4; r++) {
            int row = row0 + wr + i * 16 + quad * 4 + r;
            if (row >= M) continue;
            int w8 = __builtin_amdgcn_cvt_pk_fp8_f32(acc[i][0][r], acc[i][1][r], 0, false);
            w8 = __builtin_amdgcn_cvt_pk_fp8_f32(acc[i][2][r], acc[i][3][r], w8, true);
            Cp[(size_t)row * 256 + D] = (unsigned)w8;
        }
    }
}

/* ---------- layer-1 fused softmax+aggregation, bias+ELU ----------
   R20: R15's LDS-phase structure (best measured), with:
   - phase 1 = ONE coalesced contiguous load of precomputed weights (wcsr in
     CSR order; lane (h,g) reads wcsr[(p0+g)*8+h] -> 256B/iter contiguous),
     replacing the random a_src gather + leaky + exp chain;
   - phase 2 = fp8 row gather, now 2-deep pipelined (2 rows in flight/wave);
   - pk_fma consume. */
__global__ __launch_bounds__(256)
void agg1_fused(const int* __restrict__ rowstart, const int* __restrict__ degv,
                const int* __restrict__ csr_src,
                const unsigned* __restrict__ h1p,     /* [N][256] fp8 dwords */
                const float* __restrict__ wcsr,       /* [E][8] f32 weights */
                const float* __restrict__ b1, unsigned short* __restrict__ out1)
{
    const int t   = threadIdx.x;
    const int sub = t >> 6;            /* node within block: 0..3 (= wave) */
    const int tl  = t & 63;            /* lane within node */
    const int h   = tl >> 3;           /* head (all 16 channels of tl in this head) */
    const int g   = tl & 7;            /* slot within phase-1 stride group */
    const int d   = blockIdx.x * 4 + sub;

    __shared__ float exps[4][CAP * 8];
    __shared__ int   srcs[4][CAP];

    const int start = rowstart[d];
    const int deg   = degv[d];
    const uint4* __restrict__ h1v = reinterpret_cast<const uint4*>(h1p);  /* row = 64 uint4 */

    float denom_part = 0.f;
    f32x2 acc[8];
#pragma unroll
    for (int k = 0; k < 8; k++) acc[k] = (f32x2){0.f, 0.f};

    for (int c0 = 0; c0 < deg; c0 += CAP) {
        const int cend = min(deg - c0, CAP);
        /* phase 1: coalesced weight load (wcsr is CSR-ordered) + src indices */
        for (int c = g; c < cend; c += 8) {
            int p = start + c0 + c;
            if (h == 0) srcs[sub][c] = csr_src[p];
            float ex = wcsr[(size_t)p * 8 + h];
            exps[sub][c * 8 + h] = ex;
            denom_part += ex;
        }
        wave_sync();
        /* phase 2: 2-deep pipelined fp8 gather */
        {
            int   s0 = srcs[sub][0];
            float w0 = exps[sub][h];
            uint4 u0 = h1v[(size_t)s0 * 64 + tl];
            float w1 = 0.f; uint4 u1 = u0;
            if (1 < cend) {
                int s1 = srcs[sub][1];
                w1 = exps[sub][8 + h];
                u1 = h1v[(size_t)s1 * 64 + tl];
            }
            for (int c = 0; c < cend; c++) {
                float wn = 0.f; uint4 un = u0;
                if (c + 2 < cend) {
                    int sn = srcs[sub][c + 2];
                    wn = exps[sub][(c + 2) * 8 + h];
                    un = h1v[(size_t)sn * 64 + tl];
                }
                f32x2 w2; w2.x = w0; w2.y = w0;
#pragma unroll
                for (int dw = 0; dw < 4; dw++) {
                    unsigned wd = (&u0.x)[dw];
                    f32x2 lo = __builtin_amdgcn_cvt_pk_f32_fp8((int)wd, false);
                    f32x2 hi = __builtin_amdgcn_cvt_pk_f32_fp8((int)wd, true);
                    acc[dw * 2 + 0] = pk_fma(lo, w2, acc[dw * 2 + 0]);
                    acc[dw * 2 + 1] = pk_fma(hi, w2, acc[dw * 2 + 1]);
                }
                w0 = w1; u0 = u1; w1 = wn; u1 = un;
            }
        }
        wave_sync();
    }
    /* denominator: reduce over the 8 lanes of this head */
#pragma unroll
    for (int o = 1; o < 8; o <<= 1) denom_part += __shfl_xor(denom_part, o);
    const float dinv = 1.f / (denom_part + 1e-16f);

    /* bias (gathered at original channels) + ELU, write bf16 slots 16tl..16tl+15 */
    unsigned short ov[16];
#pragma unroll
    for (int e = 0; e < 16; e++) {
        float v = ((e & 1) ? acc[e >> 1].y : acc[e >> 1].x) * dinv + b1[slotP(16 * tl + e)];
        v = v > 0.f ? v : __expf(v) - 1.f;
        ov[e] = f2bf(v);
    }
    uint4* op = reinterpret_cast<uint4*>(out1 + (size_t)d * HC + 16 * tl);
    op[0] = *reinterpret_cast<uint4*>(&ov[0]);
    op[1] = *reinterpret_cast<uint4*>(&ov[8]);
}

/* ---------- layer-2 MFMA GEMM + fused att2 dots ---------- */
__global__ __launch_bounds__(256)
void gemm2_mfma(const unsigned short* __restrict__ A,
                const unsigned short* __restrict__ Bt,
                unsigned short* __restrict__ C,
                const float* __restrict__ att_src2, const float* __restrict__ att_dst2,
                float* __restrict__ a_src2, float* __restrict__ a_dst2, int M)
{
    __shared__ unsigned short Al[64 * 64];
    __shared__ unsigned short Bl[64 * 64];
    const int tid  = threadIdx.x;
    const int wave = tid >> 6, lane = tid & 63;
    const int quad = lane >> 4, l16 = lane & 15;
    const int wr = wave * 16;
    const int row0 = blockIdx.x * 64;

    f32x4 acc[4];
#pragma unroll
    for (int j = 0; j < 4; j++) acc[j] = (f32x4){0.f, 0.f, 0.f, 0.f};

    for (int k0 = 0; k0 < HC; k0 += 64) {
#pragma unroll
        for (int p = 0; p < 2; p++) {           /* A: 64 rows x 64 bf16, swizzled */
            int idx = tid + 256 * p;
            int r = idx >> 3, q = idx & 7;
            async_cp16(A + (size_t)(row0 + r) * HC + k0 + ((q ^ (r & 7)) * 8),
                       Al + (size_t)(wave * 64 + 256 * p) * 8);
        }
#pragma unroll
        for (int p = 0; p < 2; p++) {           /* B^T: 64 rows x 64 bf16, swizzled */
            int idx = tid + 256 * p;
            int r = idx >> 3, q = idx & 7;
            async_cp16(Bt + (size_t)r * HC + k0 + ((q ^ (r & 7)) * 8),
                       Bl + (size_t)(wave * 64 + 256 * p) * 8);
        }
        __syncthreads();
#pragma unroll
        for (int kh = 0; kh < 2; kh++) {
            const int cx = (kh * 4 + quad) ^ (l16 & 7);
            bf16x8 af, bg[4];
            af = *reinterpret_cast<const bf16x8*>(Al + ((wr + l16) * 8 + cx) * 8);
#pragma unroll
            for (int j = 0; j < 4; j++)
                bg[j] = *reinterpret_cast<const bf16x8*>(Bl + ((j * 16 + l16) * 8 + cx) * 8);
#pragma unroll
            for (int j = 0; j < 4; j++)
                acc[j] = __builtin_amdgcn_mfma_f32_16x16x32_bf16(af, bg[j], acc[j], 0, 0, 0);
        }
        __syncthreads();
    }
    float av[4], dv[4];
#pragma unroll
    for (int j = 0; j < 4; j++) {
        av[j] = att_src2[j * 16 + l16];
        dv[j] = att_dst2[j * 16 + l16];
    }
#pragma unroll
    for (int r = 0; r < 4; r++) {
        int row = row0 + wr + quad * 4 + r;
        float ps = 0.f, pd = 0.f;
#pragma unroll
        for (int j = 0; j < 4; j++) {
            float cc = acc[j][r];
            int col = j * 16 + l16;
            if (row < M) C[(size_t)row * OUTC + col] = f2bf(cc);
            ps += cc * av[j];
            pd += cc * dv[j];
        }
#pragma unroll
        for (int o = 1; o < 16; o <<= 1) {
            ps += __shfl_xor(ps, o);
            pd += __shfl_xor(pd, o);
        }
        if (l16 == 0 && row < M) {
            a_src2[row] = ps;
            a_dst2[row] = pd;
        }
    }
}

/* ---------- layer-2 fused softmax+agg + bias + log_softmax ---------- */
__global__ __launch_bounds__(256)
void agg2_lsm(const int* __restrict__ rowstart, const int* __restrict__ degv,
              const int* __restrict__ csr_src,
              const unsigned short* __restrict__ h2,
              const float* __restrict__ a_src2, const float* __restrict__ a_dst2,
              const float* __restrict__ b2, float* __restrict__ out)
{
    const int t = threadIdx.x;
    const int sub  = t >> 6;
    const int lane = t & 63;
    const int eo   = lane >> 4;        /* edge offset 0..3 */
    const int cq   = lane & 15;        /* channel quad: channels 4cq..4cq+3 */
    const int d = blockIdx.x * 4 + sub;

    __shared__ float exs[4][CAP];
    __shared__ int   ss[4][CAP];

    const int start = rowstart[d];
    const int deg   = degv[d];

    const float adst = a_dst2[d];
    const uint2* __restrict__ h2v = reinterpret_cast<const uint2*>(h2);  /* row = 16 uint2 */
    float denom_part = 0.f;
    float ax = 0.f, ay = 0.f, az = 0.f, aw = 0.f;

    for (int c0 = 0; c0 < deg; c0 += CAP) {
        const int cend = min(deg - c0, CAP);
        for (int c = lane; c < cend; c += 64) {
            int s = csr_src[start + c0 + c];
            ss[sub][c] = s;
            float a = a_src2[s] + adst;
            float v = a > 0.f ? a : NEG_SLOPE * a;
            float ex = __expf(v);
            exs[sub][c] = ex;
            denom_part += ex;
        }
        wave_sync();
        {
            int   cc = eo;
            float w0 = (cc < cend) ? exs[sub][cc] : 0.f;
            int   s0 = (cc < cend) ? ss[sub][cc] : ss[sub][0];
            uint2 u0 = h2v[(size_t)s0 * 16 + cq];
            for (int c = 0; c + 4 < cend; c += 4) {
                int cc1 = c + 4 + eo;
                float w1 = (cc1 < cend) ? exs[sub][cc1] : 0.f;
                int   s1 = (cc1 < cend) ? ss[sub][cc1] : ss[sub][0];
                uint2 u1 = h2v[(size_t)s1 * 16 + cq];
                ax += w0 * __uint_as_float(u0.x << 16);
                ay += w0 * __uint_as_float(u0.x & 0xFFFF0000u);
                az += w0 * __uint_as_float(u0.y << 16);
                aw += w0 * __uint_as_float(u0.y & 0xFFFF0000u);
                w0 = w1; s0 = s1; u0 = u1;
            }
            ax += w0 * __uint_as_float(u0.x << 16);
            ay += w0 * __uint_as_float(u0.x & 0xFFFF0000u);
            az += w0 * __uint_as_float(u0.y << 16);
            aw += w0 * __uint_as_float(u0.y & 0xFFFF0000u);
        }
        wave_sync();
    }
    ax += __shfl_xor(ax, 16); ax += __shfl_xor(ax, 32);
    ay += __shfl_xor(ay, 16); ay += __shfl_xor(ay, 32);
    az += __shfl_xor(az, 16); az += __shfl_xor(az, 32);
    aw += __shfl_xor(aw, 16); aw += __shfl_xor(aw, 32);
#pragma unroll
    for (int o = 32; o > 0; o >>= 1) denom_part += __shfl_xor(denom_part, o);
    const float dinv = 1.f / (denom_part + 1e-16f);

    float4 bb = reinterpret_cast<const float4*>(b2)[cq];
    float v0 = ax * dinv + bb.x;
    float v1 = ay * dinv + bb.y;
    float v2 = az * dinv + bb.z;
    float v3 = aw * dinv + bb.w;
    float m = fmaxf(fmaxf(v0, v1), fmaxf(v2, v3));
#pragma unroll
    for (int o = 1; o < 16; o <<= 1) m = fmaxf(m, __shfl_xor(m, o));
    float ex = __expf(v0 - m) + __expf(v1 - m) + __expf(v2 - m) + __expf(v3 - m);
    float ssum = ex;
#pragma unroll
    for (int o = 1; o < 16; o <<= 1) ssum += __shfl_xor(ssum, o);
    if (eo == 0) {
        float lg = __logf(ssum);
        reinterpret_cast<float4*>(out + (size_t)d * OUTC)[cq] =
            make_float4(v0 - m - lg, v1 - m - lg, v2 - m - lg, v3 - m - lg);
    }
}

extern "C" void kernel_launch(void* const* d_in, const int* in_sizes, int n_in,
                              void* d_out, int out_size, void* d_ws, size_t ws_size,
                              hipStream_t stream)
{
    const float* x   = (const float*)d_in[0];
    const int*   ei  = (const int*)d_in[1];
    const float* W1  = (const float*)d_in[2];
    const float* as1 = (const float*)d_in[3];
    const float* ad1 = (const float*)d_in[4];
    const float* b1  = (const float*)d_in[5];
    const float* W2  = (const float*)d_in[6];
    const float* as2 = (const float*)d_in[7];
    const float* ad2 = (const float*)d_in[8];
    const float* b2  = (const float*)d_in[9];

    char* p = (char*)d_ws;
    auto alloc = [&](size_t bytes) { char* r = p; p += (bytes + 255) & ~(size_t)255; return r; };

    /* region 0: h1p (fp8, 30.72 MB; sized 61.44) — dead after agg1; layer-2 aliases it */
    char* region0 = (char*)alloc((size_t)N_NODES * HC * 2);
    unsigned* h1p = (unsigned*)region0;

    /* region 1: out1 (bf16 slot-layout, 61.44 MB); xb/W1t (dead after gemm1) alias it */
    char* region1 = (char*)alloc((size_t)N_NODES * HC * 2);
    unsigned short* out1 = (unsigned short*)region1;
    unsigned short* xb   = (unsigned short*)region1;
    unsigned short* W1t  = (unsigned short*)(region1 + (size_t)N_NODES * F_IN * 2 + 256);

    unsigned short* W2t = (unsigned short*)alloc((size_t)OUTC * HC * 2);
    float* vsd = (float*)alloc(16 * 256 * 4);
    float* wcsr = (float*)alloc((size_t)E_TOT * 8 * 4);   /* 10.56 MB */

    float* a_src1   = (float*)alloc((size_t)N_NODES * HEADS * 4);
    float* a_dst1   = (float*)alloc((size_t)N_NODES * HEADS * 4);
    int*   deg      = (int*)alloc((size_t)(N_NODES + 1) * 4);  /* +1: alloc counter */
    int*   counter  = deg + N_NODES;
    int*   rowstart = (int*)alloc((size_t)N_NODES * 4);
    int*   cursor   = (int*)alloc((size_t)N_NODES * 4);
    int*   csr_src  = (int*)alloc((size_t)E_TOT * 4);

    /* layer-2 buffers aliased into region0 */
    char* q = region0;
    auto alias = [&](size_t bytes) { char* r = q; q += (bytes + 255) & ~(size_t)255; return r; };
    unsigned short* h2 = (unsigned short*)alias((size_t)N_NODES * OUTC * 2);
    float* a_src2  = (float*)alias((size_t)N_NODES * 4);
    float* a_dst2  = (float*)alias((size_t)N_NODES * 4);

    hipMemsetAsync(deg, 0, (size_t)(N_NODES + 1) * 4, stream);

    /* v = W1 . att (f32, tiny) */
    vsrc_kernel<<<16, 256, 0, stream>>>(W1, as1, ad1, vsd);

    /* fused prep: (x->bf16 + f32 att dots) | deg | W1t | W2t */
    prep_kernel<<<NB_PREP, 256, 0, stream>>>(x, xb, W1, W1t, W2, W2t, ei, deg,
                                             vsd, a_src1, a_dst1);

    /* CSR build; scatter also precomputes per-edge softmax numerators */
    alloc_kernel<<<(N_NODES + 255) / 256, 256, 0, stream>>>(deg, rowstart, cursor, counter);
    scatter_kernel<<<(E_TOT + 255) / 256, 256, 0, stream>>>(ei, cursor, csr_src,
                                                            a_src1, a_dst1, wcsr);

    /* layer 1 */
    gemm1_mfma<<<dim3(HC / 128, (N_NODES + 127) / 128), 256, 0, stream>>>(
        xb, W1t, h1p, N_NODES);
    agg1_fused<<<N_NODES / 4, 256, 0, stream>>>(rowstart, deg, csr_src, h1p, wcsr, b1, out1);

    /* layer 2 (h1p dead; aliased buffers safe, stream-ordered) */
    gemm2_mfma<<<(N_NODES + 63) / 64, 256, 0, stream>>>(
        out1, W2t, h2, as2, ad2, a_src2, a_dst2, N_NODES);
    agg2_lsm<<<N_NODES / 4, 256, 0, stream>>>(rowstart, deg, csr_src, h2, a_src2, a_dst2, b2, (float*)d_out);
}